// Round 10
// baseline (113.455 us; speedup 1.0000x reference)
//
#include <hip/hip_runtime.h>

// Pairwise cosine similarity: C[i][j] = <x_i/||x_i||, y_j/||y_j||>
// x,y: [8192][512] f32.  Out: [8192][8192] f32.
// Stage 1: row-normalize -> bf16 in d_ws (fused single launch).
// Stage 2: 128x256-tile BK=32 8-phase bf16 MFMA GEMM, 4 waves, 48KB LDS,
//   2 blocks/CU. Same counted-VMCNT(2) skeleton as R9 (proven) with A/B
//   staging roles mirrored (A=2 instr/tile, B=4 instr/tile).
// R10 experiment: each wave owns 32 FULL-WIDTH rows (256 cols), so the
//   epilogue emits FULL-WAVE 1KB-CONTIGUOUS plain stores (the harness
//   fill's geometry, which shows FETCH~=0 for 1GB written) via a
//   barrier-free per-wave LDS strip. Tests whether the 266MB
//   write-allocate HBM fetch (the dominant removable traffic term;
//   we're at ~88% BW with it) is elided by full-wave store runs.

typedef __attribute__((ext_vector_type(8))) short bf16x8;
typedef __attribute__((ext_vector_type(4))) float f32x4;
typedef __attribute__((ext_vector_type(8))) unsigned short ushort8;

#define M_DIM 8192
#define N_DIM 8192
#define K_DIM 512

static __device__ __forceinline__ unsigned short f32_to_bf16(float f) {
  unsigned int u = __float_as_uint(f);
  u = (u + 0x7FFFu + ((u >> 16) & 1u)) >> 16;  // round-to-nearest-even
  return (unsigned short)u;
}

// One wave per row; handles x rows [0,8192) and y rows [8192,16384).
__global__ __launch_bounds__(256) void normalize_rows(
    const float* __restrict__ x, const float* __restrict__ y,
    unsigned short* __restrict__ out) {
  const int wid = threadIdx.x >> 6;
  const int lane = threadIdx.x & 63;
  const int row = (blockIdx.x << 2) + wid;
  const float* src = row < M_DIM ? x + (size_t)row * K_DIM
                                 : y + (size_t)(row - M_DIM) * K_DIM;
  const float4* r = (const float4*)src;
  float4 v0 = r[lane * 2];
  float4 v1 = r[lane * 2 + 1];
  float ss = v0.x * v0.x + v0.y * v0.y + v0.z * v0.z + v0.w * v0.w +
             v1.x * v1.x + v1.y * v1.y + v1.z * v1.z + v1.w * v1.w;
#pragma unroll
  for (int off = 32; off; off >>= 1) ss += __shfl_xor(ss, off, 64);
  const float s = 1.0f / fmaxf(sqrtf(ss), 1e-8f);
  const float f[8] = {v0.x, v0.y, v0.z, v0.w, v1.x, v1.y, v1.z, v1.w};
  union { ushort8 v; unsigned short u[8]; } o;
#pragma unroll
  for (int i = 0; i < 8; ++i) o.u[i] = f32_to_bf16(f[i] * s);
  *(ushort8*)(out + (size_t)row * K_DIM + lane * 8) = o.v;
}

static __device__ __forceinline__ void gl16(const unsigned short* g, char* l) {
  __builtin_amdgcn_global_load_lds(
      (const __attribute__((address_space(1))) unsigned int*)g,
      (__attribute__((address_space(3))) unsigned int*)l, 16, 0, 0);
}

#define BAR() __builtin_amdgcn_s_barrier()
#define SBAR() __builtin_amdgcn_sched_barrier(0)
#define LGKM0() do { asm volatile("s_waitcnt lgkmcnt(0)" ::: "memory"); \
                     __builtin_amdgcn_sched_barrier(0); } while (0)
#define VMCNT(n) do { asm volatile("s_waitcnt vmcnt(" #n ")" ::: "memory"); \
                      __builtin_amdgcn_sched_barrier(0); } while (0)

// LDS per parity p (stride 24576): A [0,8K): row r (0..127) at r*64,
// 16B slot s stored at (s ^ (r&3))*16; B [8K,24K): row (0..255) same.
__global__ __launch_bounds__(256, 2) void cosgemm(
    const unsigned short* __restrict__ A,   // xn bf16 [8192][512]
    const unsigned short* __restrict__ B,   // yn bf16 [8192][512]
    float* __restrict__ C) {                // [8192][8192]
  extern __shared__ char smem[];  // 49152 B

  const int tid = threadIdx.x;
  const int lane = tid & 63;
  const int wid = tid >> 6;       // 0..3; wave owns C rows [wid*32, +32)
  const int lr16 = lane & 15;
  const int hq = lane >> 4;       // 0..3  (k slot group)
  const int sw = hq ^ (lr16 & 3); // swizzled ds_read 16B slot

  // XCD banding: xcd = bid&7 owns by in {8x..8x+7}; sweep bx per band.
  const int bid = blockIdx.x;                // 0..2047
  const int idx = bid >> 3;                  // 0..255
  const int by = ((bid & 7) << 3) + (idx & 7);   // 0..63
  const int bx = idx >> 3;                   // 0..31
  const int row0 = by << 7;                  // A rows (128)
  const int col0 = bx << 8;                  // B rows / C cols (256)

  // staging source: gl16 call covers rows base + (lane>>2) (16 rows),
  // global 16B slot = (lane&3) ^ (row&3).
  const int srl = lane >> 2;
  const int ssl = (lane & 3) ^ (srl & 3);
  const unsigned short* pA =
      A + (size_t)(row0 + (wid << 5) + srl) * K_DIM + ssl * 8;
  const unsigned short* pB =
      B + (size_t)(col0 + (wid << 6) + srl) * K_DIM + ssl * 8;

  // stageA1: 1 gl16 (16 rows); stageB2: 2 gl16 (32 rows). T = K-tile idx.
  auto stageA1 = [&](int par, int c, int T) {
    char* l = smem + par * 24576 + (wid << 11) + (c << 10);
    gl16(pA + T * 32 + (size_t)(c << 4) * K_DIM, l);
  };
  auto stageB2 = [&](int par, int cp, int T) {
    char* l = smem + par * 24576 + 8192 + (wid << 12) + (cp << 11);
    const unsigned short* g = pB + T * 32 + (size_t)(cp << 5) * K_DIM;
    gl16(g, l);
    gl16(g + (size_t)16 * K_DIM, l + 1024);
  };

  bf16x8 af[2], bf[4];
  f32x4 acc[2][16] = {};

  auto ldA = [&](int par) {   // 2 x ds_read_b128
#pragma unroll
    for (int m = 0; m < 2; ++m) {
      const int row = (wid << 5) + m * 16 + lr16;
      af[m] = *(const bf16x8*)(smem + par * 24576 + row * 64 + (sw << 4));
    }
  };
  auto ldB = [&](int par, int g) {   // 4 x ds_read_b128 (fn = 4g..4g+3)
#pragma unroll
    for (int j = 0; j < 4; ++j) {
      const int row = (g * 4 + j) * 16 + lr16;
      bf[j] = *(const bf16x8*)(smem + par * 24576 + 8192 + row * 64 +
                               (sw << 4));
    }
  };
  auto mm = [&](int g) {  // 8 MFMA (fn group g)
    __builtin_amdgcn_s_setprio(1);
#pragma unroll
    for (int m = 0; m < 2; ++m)
#pragma unroll
      for (int j = 0; j < 4; ++j)
        acc[m][g * 4 + j] = __builtin_amdgcn_mfma_f32_16x16x32_bf16(
            af[m], bf[j], acc[m][g * 4 + j], 0, 0, 0);
    __builtin_amdgcn_s_setprio(0);
  };

  // ---- prologue: B(0) 4 instr, A(0) 2, A(1) 2; VMCNT(2) -> tile0 landed
  stageB2(0, 0, 0); stageB2(0, 1, 0);
  stageA1(0, 0, 0); stageA1(0, 1, 0);
  stageA1(1, 0, 1); stageA1(1, 1, 1);
  VMCNT(2);
  BAR(); SBAR();

  // in-flight ledger (in-order retirement), steady state:
  // P4: A(u)2,B(u)4,A(t2)2=8 -> VMCNT(2) retires u's tile, leaves A(t2).
  // P8: A(t2)2,B(t2)4,A(t3)2=8 -> VMCNT(2) retires t2, leaves A(t3).
#pragma unroll 1
  for (int j = 0; j < 8; ++j) {
    const bool st = (j < 7);
    const int u = 2 * j + 1, t2 = 2 * j + 2, t3 = 2 * j + 3;
    // P1
    ldA(0); ldB(0, 0); stageB2(1, 0, u);
    BAR(); LGKM0(); mm(0); BAR();
    // P2
    ldB(0, 1); stageB2(1, 1, u);
    BAR(); LGKM0(); mm(1); BAR();
    // P3
    ldB(0, 2); if (st) stageA1(0, 0, t2);
    BAR(); LGKM0(); mm(2); BAR();
    // P4
    ldB(0, 3); if (st) stageA1(0, 1, t2);
    BAR(); LGKM0(); mm(3);
    if (st) { VMCNT(2); } else { VMCNT(0); }
    BAR(); SBAR();
    // P5
    ldA(1); ldB(1, 0); if (st) stageB2(0, 0, t2);
    BAR(); LGKM0(); mm(0); BAR();
    // P6
    ldB(1, 1); if (st) stageB2(0, 1, t2);
    BAR(); LGKM0(); mm(1); BAR();
    // P7
    ldB(1, 2); if (st) stageA1(1, 0, t3);
    BAR(); LGKM0(); mm(2); BAR();
    // P8
    ldB(1, 3); if (st) stageA1(1, 1, t3);
    BAR(); LGKM0(); mm(3);
    if (st) { VMCNT(2); }
    BAR(); SBAR();
  }

  // ---- epilogue: barrier-free per-wave [8][258] f32 strip (8256B/wave,
  // 33KB total). All LDS dead: every wave passed the final barrier and
  // issues no further staged ds ops. Readback = full-wave 1KB-contiguous
  // plain stores (fill geometry).
  float* S = (float*)(smem + wid * 8256);
  const int crow0 = row0 + (wid << 5);
  const size_t cbase = (size_t)col0 + lane * 4;
#pragma unroll
  for (int fm = 0; fm < 2; ++fm)
#pragma unroll
    for (int h = 0; h < 2; ++h) {
      if ((hq >> 1) == h) {
#pragma unroll
        for (int fn = 0; fn < 16; ++fn)
#pragma unroll
          for (int q = 0; q < 4; ++q)
            S[((hq & 1) * 4 + q) * 258 + fn * 16 + lr16] = acc[fm][fn][q];
      }
      LGKM0();  // scatter visible to own wave's reads
#pragma unroll
      for (int r = 0; r < 8; ++r) {
        f32x4 v = *(const f32x4*)&S[r * 258 + lane * 4];
        *(f32x4*)&C[(size_t)(crow0 + fm * 16 + h * 8 + r) * N_DIM + cbase] = v;
      }
    }
}

extern "C" void kernel_launch(void* const* d_in, const int* in_sizes, int n_in,
                              void* d_out, int out_size, void* d_ws, size_t ws_size,
                              hipStream_t stream) {
  const float* x = (const float*)d_in[0];
  const float* y = (const float*)d_in[1];
  float* out = (float*)d_out;
  unsigned short* xn = (unsigned short*)d_ws;                    // 8 MB
  unsigned short* yn = xn + (size_t)M_DIM * K_DIM;               // 8 MB

  (void)hipFuncSetAttribute((const void*)cosgemm,
                            hipFuncAttributeMaxDynamicSharedMemorySize, 65536);

  normalize_rows<<<(M_DIM + N_DIM) / 4, 256, 0, stream>>>(x, y, xn);
  cosgemm<<<(M_DIM / 128) * (N_DIM / 256), 256, 49152, stream>>>(xn, yn, out);
}

// Round 11
// 111.107 us; speedup vs baseline: 1.0211x; 1.0211x over previous
//
#include <hip/hip_runtime.h>

// Pairwise cosine similarity: C[i][j] = <x_i/||x_i||, y_j/||y_j||>
// x,y: [8192][512] f32.  Out: [8192][8192] f32.
// Stage 1: row-normalize -> bf16 in d_ws (fused single launch).
// Stage 2 (R11): 128x128-tile BK=32 bf16 MFMA GEMM, 4 waves (64x64/wave,
//   acc=64 VGPR), __launch_bounds__(256,3) -> 3 waves/SIMD, TRIPLE-buffered
//   48KB LDS (3 blocks/CU), 2-tile-ahead prefetch, 2 phases/K-tile,
//   counted VMCNT(4) (never 0 mid-loop). All configs so far ran 2
//   waves/SIMD (~200 VGPR) and converged at 650-700 TF latency-bound;
//   this trades tile size for occupancy. XOR swizzle (both sides),
//   XCD 8-band ordering, nt strip epilogue (store geometry proven
//   time-neutral in R3/R5/R10; write-allocate fetch is L3-served).

typedef __attribute__((ext_vector_type(8))) short bf16x8;
typedef __attribute__((ext_vector_type(4))) float f32x4;
typedef __attribute__((ext_vector_type(8))) unsigned short ushort8;

#define M_DIM 8192
#define N_DIM 8192
#define K_DIM 512

static __device__ __forceinline__ unsigned short f32_to_bf16(float f) {
  unsigned int u = __float_as_uint(f);
  u = (u + 0x7FFFu + ((u >> 16) & 1u)) >> 16;  // round-to-nearest-even
  return (unsigned short)u;
}

// One wave per row; handles x rows [0,8192) and y rows [8192,16384).
__global__ __launch_bounds__(256) void normalize_rows(
    const float* __restrict__ x, const float* __restrict__ y,
    unsigned short* __restrict__ out) {
  const int wid = threadIdx.x >> 6;
  const int lane = threadIdx.x & 63;
  const int row = (blockIdx.x << 2) + wid;
  const float* src = row < M_DIM ? x + (size_t)row * K_DIM
                                 : y + (size_t)(row - M_DIM) * K_DIM;
  const float4* r = (const float4*)src;
  float4 v0 = r[lane * 2];
  float4 v1 = r[lane * 2 + 1];
  float ss = v0.x * v0.x + v0.y * v0.y + v0.z * v0.z + v0.w * v0.w +
             v1.x * v1.x + v1.y * v1.y + v1.z * v1.z + v1.w * v1.w;
#pragma unroll
  for (int off = 32; off; off >>= 1) ss += __shfl_xor(ss, off, 64);
  const float s = 1.0f / fmaxf(sqrtf(ss), 1e-8f);
  const float f[8] = {v0.x, v0.y, v0.z, v0.w, v1.x, v1.y, v1.z, v1.w};
  union { ushort8 v; unsigned short u[8]; } o;
#pragma unroll
  for (int i = 0; i < 8; ++i) o.u[i] = f32_to_bf16(f[i] * s);
  *(ushort8*)(out + (size_t)row * K_DIM + lane * 8) = o.v;
}

static __device__ __forceinline__ void gl16(const unsigned short* g, char* l) {
  __builtin_amdgcn_global_load_lds(
      (const __attribute__((address_space(1))) unsigned int*)g,
      (__attribute__((address_space(3))) unsigned int*)l, 16, 0, 0);
}

#define BAR() __builtin_amdgcn_s_barrier()
#define SBAR() __builtin_amdgcn_sched_barrier(0)
#define LGKM0() do { asm volatile("s_waitcnt lgkmcnt(0)" ::: "memory"); \
                     __builtin_amdgcn_sched_barrier(0); } while (0)
#define VMCNT(n) do { asm volatile("s_waitcnt vmcnt(" #n ")" ::: "memory"); \
                      __builtin_amdgcn_sched_barrier(0); } while (0)

// LDS: buf[3] x {A 8KB, B 8KB} (stride 16384). Row r (0..127) at r*64B;
// 16B slot s stored at (s ^ (r&3))*16 (XOR swizzle, both sides).
__global__ __launch_bounds__(256, 3) void cosgemm(
    const unsigned short* __restrict__ A,   // xn bf16 [8192][512]
    const unsigned short* __restrict__ B,   // yn bf16 [8192][512]
    float* __restrict__ C) {                // [8192][8192]
  extern __shared__ char smem[];  // 49152 B

  const int tid = threadIdx.x;
  const int lane = tid & 63;
  const int wid = tid >> 6;       // 0..3
  const int wm = wid >> 1;        // 0..1 (row half: 64 rows)
  const int wn = wid & 1;         // 0..1 (col half: 64 cols)
  const int lr16 = lane & 15;
  const int hq = lane >> 4;       // 0..3 (k slot)
  const int sw = hq ^ (lr16 & 3); // swizzled ds_read 16B slot

  // XCD banding: xcd = bid&7 owns by in {8x..8x+7}; sweep bx per band.
  const int bid = blockIdx.x;                 // 0..4095
  const int idx = bid >> 3;                   // 0..511
  const int by = ((bid & 7) << 3) + (idx & 7);    // 0..63
  const int bx = idx >> 3;                    // 0..63
  const int row0 = by << 7;
  const int col0 = bx << 7;

  // staging: gl16 covers 64 rows x 4 slots; thread t -> row base+ (t>>2),
  // global slot (t&3) ^ (row&3).
  const int srl = lane >> 2;                 // 0..15
  const int ssl = (lane & 3) ^ (srl & 3);
  const unsigned short* pA =
      A + (size_t)(row0 + (wid << 4) + srl) * K_DIM + ssl * 8;
  const unsigned short* pB =
      B + (size_t)(col0 + (wid << 4) + srl) * K_DIM + ssl * 8;

  auto stageA = [&](int buf, int h, int T) {  // 1 gl16: A rows h*64..+64
    char* l = smem + buf * 16384 + (h << 12) + (wid << 10);
    gl16(pA + T * 32 + (size_t)(h << 6) * K_DIM, l);
  };
  auto stageB = [&](int buf, int h, int T) {
    char* l = smem + buf * 16384 + 8192 + (h << 12) + (wid << 10);
    gl16(pB + T * 32 + (size_t)(h << 6) * K_DIM, l);
  };

  bf16x8 af[4], bf[4];
  f32x4 acc[4][4] = {};

  auto ldA = [&](int buf) {   // 4 x ds_read_b128
#pragma unroll
    for (int m = 0; m < 4; ++m) {
      const int row = (wm << 6) + m * 16 + lr16;
      af[m] = *(const bf16x8*)(smem + buf * 16384 + row * 64 + (sw << 4));
    }
  };
  auto ldB = [&](int buf, int g) {  // 2 x ds_read_b128 (fn = 2g, 2g+1)
#pragma unroll
    for (int j = 0; j < 2; ++j) {
      const int row = (wn << 6) + (g * 2 + j) * 16 + lr16;
      bf[g * 2 + j] = *(const bf16x8*)(smem + buf * 16384 + 8192 + row * 64 +
                                       (sw << 4));
    }
  };
  auto mm = [&](int g) {  // 8 MFMA (fn pair g)
    __builtin_amdgcn_s_setprio(1);
#pragma unroll
    for (int m = 0; m < 4; ++m)
#pragma unroll
      for (int j = 0; j < 2; ++j)
        acc[m][g * 2 + j] = __builtin_amdgcn_mfma_f32_16x16x32_bf16(
            af[m], bf[g * 2 + j], acc[m][g * 2 + j], 0, 0, 0);
    __builtin_amdgcn_s_setprio(0);
  };

  // ---- prologue: T0 -> buf0 (4 units), T1 -> buf1 (4); VMCNT(4) = T0 in.
  stageA(0, 0, 0); stageA(0, 1, 0); stageB(0, 0, 0); stageB(0, 1, 0);
  stageA(1, 0, 1); stageA(1, 1, 1); stageB(1, 0, 1); stageB(1, 1, 1);
  VMCNT(4);
  BAR(); SBAR();

  // ledger: 4 gl16/tile. end of iter t: outstanding = (t+1)'s 4 (staged
  // in iter t-1) + (t+2)'s 4 (this iter) -> VMCNT(4) retires t+1's,
  // leaves t+2's. Buffer (t+2)%3 was last read in iter t-1 (done).
#pragma unroll 1
  for (int t = 0; t < 16; ++t) {
    const int cb = t % 3, nb = (t + 2) % 3;
    const bool st = (t < 14);
    // Phase A: af(4) + bf01(2) reads; stage (t+2).A
    ldA(cb); ldB(cb, 0);
    if (st) { stageA(nb, 0, t + 2); stageA(nb, 1, t + 2); }
    BAR(); LGKM0(); mm(0); BAR();
    // Phase B: bf23(2) reads; stage (t+2).B
    ldB(cb, 1);
    if (st) { stageB(nb, 0, t + 2); stageB(nb, 1, t + 2); }
    BAR(); LGKM0(); mm(1);
    if (st) { VMCNT(4); } else { VMCNT(0); }
    BAR(); SBAR();
  }

  // ---- epilogue: per-wave [16][68] f32 strip (4352B at smem+wid*4352);
  // all LDS dead (final VMCNT(0), all reads consumed, trailing barrier).
  float* S = (float*)(smem + wid * 4352);
  const int crow0 = row0 + (wm << 6);
  const int ccol0 = col0 + (wn << 6);
#pragma unroll
  for (int fm = 0; fm < 4; ++fm) {
#pragma unroll
    for (int fn = 0; fn < 4; ++fn)
#pragma unroll
      for (int q = 0; q < 4; ++q)
        S[(hq * 4 + q) * 68 + fn * 16 + lr16] = acc[fm][fn][q];
#pragma unroll
    for (int r = 0; r < 4; ++r) {
      f32x4 v = *(const f32x4*)&S[(r * 4 + hq) * 68 + lr16 * 4];
      __builtin_nontemporal_store(
          v, (f32x4*)&C[(size_t)(crow0 + fm * 16 + r * 4 + hq) * N_DIM +
                        ccol0 + lr16 * 4]);
    }
  }
}

extern "C" void kernel_launch(void* const* d_in, const int* in_sizes, int n_in,
                              void* d_out, int out_size, void* d_ws, size_t ws_size,
                              hipStream_t stream) {
  const float* x = (const float*)d_in[0];
  const float* y = (const float*)d_in[1];
  float* out = (float*)d_out;
  unsigned short* xn = (unsigned short*)d_ws;                    // 8 MB
  unsigned short* yn = xn + (size_t)M_DIM * K_DIM;               // 8 MB

  (void)hipFuncSetAttribute((const void*)cosgemm,
                            hipFuncAttributeMaxDynamicSharedMemorySize, 49152);

  normalize_rows<<<(M_DIM + N_DIM) / 4, 256, 0, stream>>>(x, y, xn);
  cosgemm<<<(M_DIM / 128) * (N_DIM / 128), 256, 49152, stream>>>(xn, yn, out);
}